// Round 1
// baseline (289.516 us; speedup 1.0000x reference)
//
#include <hip/hip_runtime.h>

#define NN 4096     // nodes
#define HC 8        // heads
#define DC 32       // dim per head
#define OC 256      // out channels = HC*DC
#define KC 256      // in channels
#define CF 6        // curvature features

typedef __bf16 bf16_t;
typedef bf16_t bf16x8 __attribute__((ext_vector_type(8)));
typedef float f32x4 __attribute__((ext_vector_type(4)));
typedef int i32x4 __attribute__((ext_vector_type(4)));

#if defined(__has_builtin)
#if __has_builtin(__builtin_amdgcn_exp2f)
#define EXP2F(x) __builtin_amdgcn_exp2f(x)
#else
#define EXP2F(x) exp2f(x)
#endif
#else
#define EXP2F(x) exp2f(x)
#endif

// ---------------------------------------------------------------------------
// Kernel 1: h = x @ W^T   (4096x256) = x(4096x256) * W(256x256)^T, fp32.
// 64x64 tile per 256-thread block, 4x4 micro-tile per thread, LDS staged
// K-transposed (As[k][i]) so inner reads are b128.
// ---------------------------------------------------------------------------
__global__ __launch_bounds__(256) void gemm_h(const float* __restrict__ x,
                                              const float* __restrict__ W,
                                              float* __restrict__ h) {
  __shared__ float As[16][68];
  __shared__ float Bs[16][68];
  const int t = threadIdx.x;
  const int i0 = blockIdx.x * 64;
  const int c0 = blockIdx.y * 64;
  const int tx = t & 15;
  const int ty = t >> 4;
  const int lr = t >> 2;        // 0..63 row within tile
  const int lk = (t & 3) * 4;   // 0,4,8,12
  float acc[4][4] = {};
  for (int kk = 0; kk < KC; kk += 16) {
    f32x4 av = *(const f32x4*)&x[(i0 + lr) * KC + kk + lk];
    f32x4 wv = *(const f32x4*)&W[(c0 + lr) * KC + kk + lk];
    __syncthreads();
    As[lk + 0][lr] = av[0]; As[lk + 1][lr] = av[1];
    As[lk + 2][lr] = av[2]; As[lk + 3][lr] = av[3];
    Bs[lk + 0][lr] = wv[0]; Bs[lk + 1][lr] = wv[1];
    Bs[lk + 2][lr] = wv[2]; Bs[lk + 3][lr] = wv[3];
    __syncthreads();
#pragma unroll
    for (int k = 0; k < 16; ++k) {
      f32x4 a = *(const f32x4*)&As[k][ty * 4];
      f32x4 b = *(const f32x4*)&Bs[k][tx * 4];
#pragma unroll
      for (int r = 0; r < 4; ++r)
#pragma unroll
        for (int u = 0; u < 4; ++u)
          acc[r][u] += a[r] * b[u];
    }
  }
#pragma unroll
  for (int r = 0; r < 4; ++r) {
    f32x4 o;
    o[0] = acc[r][0]; o[1] = acc[r][1]; o[2] = acc[r][2]; o[3] = acc[r][3];
    *(f32x4*)&h[(i0 + ty * 4 + r) * OC + c0 + tx * 4] = o;
  }
}

// ---------------------------------------------------------------------------
// Kernel 2: prep — e_l2[i,h] = log2e * sum_d h*a_l ; e_r2T[h][i] likewise;
// cfT[f][j] transpose of curv feats; Wc2[h][f] = Wc*gate*log2e.
// ---------------------------------------------------------------------------
__global__ __launch_bounds__(256) void prep(const float* __restrict__ h,
                                            const float* __restrict__ cfeat,
                                            const float* __restrict__ a_l,
                                            const float* __restrict__ a_r,
                                            const float* __restrict__ Wc,
                                            const float* __restrict__ gate,
                                            float* __restrict__ e_l2,
                                            float* __restrict__ e_r2T,
                                            float* __restrict__ cfT,
                                            float* __restrict__ Wc2) {
  const float LOG2E = 1.44269504088896340736f;
  int gid = blockIdx.x * 256 + threadIdx.x;
  if (gid < NN * HC) {
    int i = gid >> 3, hh = gid & 7;
    const float* hp = h + i * OC + hh * DC;
    const float* al = a_l + hh * DC;
    const float* ar = a_r + hh * DC;
    float el = 0.f, er = 0.f;
#pragma unroll
    for (int d = 0; d < DC; d += 4) {
      f32x4 hv = *(const f32x4*)(hp + d);
      f32x4 lv = *(const f32x4*)(al + d);
      f32x4 rv = *(const f32x4*)(ar + d);
#pragma unroll
      for (int u = 0; u < 4; ++u) { el += hv[u] * lv[u]; er += hv[u] * rv[u]; }
    }
    e_l2[gid] = el * LOG2E;
    e_r2T[hh * NN + i] = er * LOG2E;
  }
  if (gid < NN * CF) {
    int j = gid / CF, f = gid % CF;
    cfT[f * NN + j] = cfeat[gid];
  }
  if (gid < HC * CF) {
    Wc2[gid] = Wc[gid] * gate[0] * LOG2E;
  }
}

// ---------------------------------------------------------------------------
// Kernel 3: hT[hd][j] = (bf16) h[j][hd]  — 64x64 LDS tile transpose.
// ---------------------------------------------------------------------------
__global__ __launch_bounds__(256) void h_to_bf16T(const float* __restrict__ h,
                                                  bf16_t* __restrict__ hT) {
  __shared__ float tile[64][65];
  const int t = threadIdx.x;
  const int j0 = blockIdx.x * 64;   // row block of h (node index)
  const int c0 = blockIdx.y * 64;   // col block (hd index)
  const int cc = t & 63;
  const int r0 = t >> 6;            // 0..3
  for (int rr = 0; rr < 64; rr += 4)
    tile[rr + r0][cc] = h[(j0 + rr + r0) * OC + c0 + cc];
  __syncthreads();
  for (int rr = 0; rr < 64; rr += 4) {
    int hd = rr + r0;
    hT[(size_t)(c0 + hd) * NN + j0 + cc] = (bf16_t)tile[cc][hd];
  }
}

// ---------------------------------------------------------------------------
// Kernel 4: fused masked attention.
// Grid: 256 blocks (16 i-rows each) x 512 threads (8 waves).
// Wave w handles j-chunks {w, w+8, ...} of 32 j's; all 8 heads.
// Lane computes P directly in MFMA A-fragment layout:
//   m = lane&15 (i row), k = (lane>>4)*8 + t (j within chunk).
// V fragments read from hT (B layout: n = lane&15 = d, k = quad*8+t = j).
// No online max: logits bounded (~[-2,5.5]); masked p == 0 exactly.
// ---------------------------------------------------------------------------
__global__ __launch_bounds__(512, 2) void attn(const int* __restrict__ adj,
                                               const float* __restrict__ e_l2,
                                               const float* __restrict__ e_r2T,
                                               const float* __restrict__ cfT,
                                               const float* __restrict__ Wc2,
                                               const bf16_t* __restrict__ hT,
                                               float* __restrict__ out) {
  __shared__ float Obuf[16][OC];
  __shared__ float Sbuf[16][HC];
  const int tid = threadIdx.x;
  const int w = tid >> 6;
  const int lane = tid & 63;
  const int il = lane & 15;
  const int quad = lane >> 4;
  const int ibase = blockIdx.x * 16;
  const int i = ibase + il;

  // zero the LDS accumulators
  for (int idx = tid; idx < 16 * OC; idx += 512) (&Obuf[0][0])[idx] = 0.f;
  if (tid < 16 * HC) (&Sbuf[0][0])[tid] = 0.f;
  __syncthreads();

  // per-lane loop constants
  float cfi[CF];
#pragma unroll
  for (int f = 0; f < CF; ++f) cfi[f] = cfT[f * NN + i];
  float el[HC];
  {
    f32x4 e0 = *(const f32x4*)&e_l2[i * HC];
    f32x4 e1 = *(const f32x4*)&e_l2[i * HC + 4];
#pragma unroll
    for (int u = 0; u < 4; ++u) { el[u] = e0[u]; el[4 + u] = e1[u]; }
  }
  float wc[HC][CF];
#pragma unroll
  for (int q = 0; q < HC * CF; ++q) (&wc[0][0])[q] = Wc2[q];  // uniform -> s_loads

  f32x4 acc[HC][2];
#pragma unroll
  for (int hh = 0; hh < HC; ++hh)
#pragma unroll
    for (int d = 0; d < 2; ++d) acc[hh][d] = (f32x4){0.f, 0.f, 0.f, 0.f};
  float S[HC] = {};

  for (int c = w; c < NN / 32; c += 8) {
    const int jb = c * 32;
    const int jq = jb + quad * 8;
    // adjacency mask (0/1) for this lane's row, 8 j's
    const int* arow = adj + (size_t)i * NN + jq;
    i32x4 m0 = *(const i32x4*)arow;
    i32x4 m1 = *(const i32x4*)(arow + 4);
    float mf[8];
#pragma unroll
    for (int u = 0; u < 4; ++u) { mf[u] = (float)m0[u]; mf[4 + u] = (float)m1[u]; }
    // |cf_i - cf_j| for 8 j's
    float ad[CF][8];
#pragma unroll
    for (int f = 0; f < CF; ++f) {
      f32x4 c0v = *(const f32x4*)&cfT[f * NN + jq];
      f32x4 c1v = *(const f32x4*)&cfT[f * NN + jq + 4];
#pragma unroll
      for (int u = 0; u < 4; ++u) {
        ad[f][u] = fabsf(cfi[f] - c0v[u]);
        ad[f][4 + u] = fabsf(cfi[f] - c1v[u]);
      }
    }
#pragma unroll
    for (int hh = 0; hh < HC; ++hh) {
      f32x4 er0 = *(const f32x4*)&e_r2T[hh * NN + jq];
      f32x4 er1 = *(const f32x4*)&e_r2T[hh * NN + jq + 4];
      float er[8];
#pragma unroll
      for (int u = 0; u < 4; ++u) { er[u] = er0[u]; er[4 + u] = er1[u]; }
      bf16x8 af;
#pragma unroll
      for (int tt = 0; tt < 8; ++tt) {
        float s = el[hh] + er[tt];
        float l = fmaxf(s, 0.2f * s);       // log2e-scaled leaky_relu
        float arg = l;
#pragma unroll
        for (int f = 0; f < CF; ++f) arg += ad[f][tt] * wc[hh][f];
        float pv = EXP2F(arg) * mf[tt];
        S[hh] += pv;
        af[tt] = (bf16_t)pv;
      }
      const bf16_t* bp0 = hT + (size_t)(hh * DC + il) * NN + jq;
      bf16x8 b0 = *(const bf16x8*)bp0;
      bf16x8 b1 = *(const bf16x8*)(bp0 + 16 * NN);
      acc[hh][0] = __builtin_amdgcn_mfma_f32_16x16x32_bf16(af, b0, acc[hh][0], 0, 0, 0);
      acc[hh][1] = __builtin_amdgcn_mfma_f32_16x16x32_bf16(af, b1, acc[hh][1], 0, 0, 0);
    }
  }

  // reduce S across the 4 quads (lanes il, il+16, il+32, il+48)
#pragma unroll
  for (int hh = 0; hh < HC; ++hh) {
    float v = S[hh];
    v += __shfl_xor(v, 16, 64);
    v += __shfl_xor(v, 32, 64);
    S[hh] = v;
  }
  if (quad == 0) {
#pragma unroll
    for (int hh = 0; hh < HC; ++hh) atomicAdd(&Sbuf[il][hh], S[hh]);
  }
  // accumulate O partials: C/D layout row = quad*4+r, col = il (+16*dhalf)
#pragma unroll
  for (int hh = 0; hh < HC; ++hh)
#pragma unroll
    for (int dh = 0; dh < 2; ++dh)
#pragma unroll
      for (int r = 0; r < 4; ++r)
        atomicAdd(&Obuf[quad * 4 + r][hh * DC + dh * 16 + il], acc[hh][dh][r]);
  __syncthreads();

  // epilogue: divide by softmax denom, coalesced store
  for (int idx = tid; idx < 16 * OC; idx += 512) {
    int row = idx >> 8;
    int hd = idx & 255;
    out[(size_t)(ibase + row) * OC + hd] = Obuf[row][hd] / Sbuf[row][hd >> 5];
  }
}

// ---------------------------------------------------------------------------
extern "C" void kernel_launch(void* const* d_in, const int* in_sizes, int n_in,
                              void* d_out, int out_size, void* d_ws, size_t ws_size,
                              hipStream_t stream) {
  const float* x    = (const float*)d_in[0];
  // d_in[1] = positions — unused by the reference
  const float* cfeat= (const float*)d_in[2];
  const int*   adj  = (const int*)d_in[3];
  const float* W    = (const float*)d_in[4];
  const float* a_l  = (const float*)d_in[5];
  const float* a_r  = (const float*)d_in[6];
  const float* Wc   = (const float*)d_in[7];
  const float* gate = (const float*)d_in[8];
  float* out = (float*)d_out;

  char* ws = (char*)d_ws;
  float*  h    = (float*)ws;                               // 4 MB
  bf16_t* hT   = (bf16_t*)(ws + (4u << 20));               // 2 MB
  float*  e_l2 = (float*)(ws + (6u << 20));                // 128 KB
  float*  e_r2T= (float*)(ws + (6u << 20) + (128u << 10)); // 128 KB
  float*  cfT  = (float*)(ws + (6u << 20) + (256u << 10)); // 96 KB
  float*  Wc2  = (float*)(ws + (6u << 20) + (384u << 10)); // 192 B

  gemm_h<<<dim3(NN / 64, OC / 64), 256, 0, stream>>>(x, W, h);
  prep<<<(NN * HC + 255) / 256, 256, 0, stream>>>(h, cfeat, a_l, a_r, Wc, gate,
                                                  e_l2, e_r2T, cfT, Wc2);
  h_to_bf16T<<<dim3(NN / 64, OC / 64), 256, 0, stream>>>(h, hT);
  attn<<<NN / 16, 512, 0, stream>>>(adj, e_l2, e_r2T, cfT, Wc2, hT, out);
}